// Round 1
// baseline (367.243 us; speedup 1.0000x reference)
//
#include <hip/hip_runtime.h>
#include <hip/hip_bf16.h>

#define NN 6144
#define INPUT 1024
#define HID 256

using frag  = __attribute__((ext_vector_type(8))) short;   // 8 bf16
using f32x4 = __attribute__((ext_vector_type(4))) float;

static __device__ __forceinline__ unsigned short bf16u(float x) {
    unsigned u = __float_as_uint(x);
    u += 0x7fff + ((u >> 16) & 1);     // RNE
    return (unsigned short)(u >> 16);
}

// ---------------- convert X -> bf16 (row-major) ----------------
__global__ __launch_bounds__(256) void k_convert_x(const float* __restrict__ X,
                                                   unsigned short* __restrict__ Xb) {
    int t = blockIdx.x * 256 + threadIdx.x;          // one float4 per thread
    float4 v = reinterpret_cast<const float4*>(X)[t];
    ushort4 o;
    o.x = bf16u(v.x); o.y = bf16u(v.y); o.z = bf16u(v.z); o.w = bf16u(v.w);
    reinterpret_cast<ushort4*>(Xb)[t] = o;
}

// ---------------- convert W -> Wt bf16 transposed [HID][INPUT] ----------------
__global__ __launch_bounds__(256) void k_convert_w(const float* __restrict__ W,
                                                   unsigned short* __restrict__ Wt) {
    int t = blockIdx.x * 256 + threadIdx.x;          // t = n*1024 + k
    int n = t >> 10, k = t & 1023;
    Wt[t] = bf16u(W[k * HID + n]);
}

// ---------------- GEMM1: h = X @ W  (bf16 MFMA, fp32 h + bf16 hT outputs) ----------------
// block 256 = 4 waves; block tile 64(M) x 64(N); wave: M16 x N64; K-steps of 32.
__global__ __launch_bounds__(256) void k_gemm1(const unsigned short* __restrict__ Xb,
                                               const unsigned short* __restrict__ Wt,
                                               float* __restrict__ h,
                                               unsigned short* __restrict__ hT) {
    int w = threadIdx.x >> 6, l = threadIdx.x & 63;
    int lm = l & 15, lq = l >> 4;
    int i0 = blockIdx.x * 64 + w * 16;
    int n0 = blockIdx.y * 64;

    f32x4 acc[4] = {};
    const unsigned short* arow = Xb + (size_t)(i0 + lm) * INPUT + lq * 8;
    const unsigned short* brow[4];
#pragma unroll
    for (int nt = 0; nt < 4; nt++)
        brow[nt] = Wt + (size_t)(n0 + nt * 16 + lm) * INPUT + lq * 8;

    for (int ks = 0; ks < INPUT; ks += 32) {
        frag a = *reinterpret_cast<const frag*>(arow + ks);
#pragma unroll
        for (int nt = 0; nt < 4; nt++) {
            frag b = *reinterpret_cast<const frag*>(brow[nt] + ks);
            acc[nt] = __builtin_amdgcn_mfma_f32_16x16x32_bf16(a, b, acc[nt], 0, 0, 0);
        }
    }
    // epilogue: C/D layout col=lane&15, row=(lane>>4)*4+reg
    int ib = i0 + lq * 4;
#pragma unroll
    for (int nt = 0; nt < 4; nt++) {
        int n = n0 + nt * 16 + lm;
#pragma unroll
        for (int r = 0; r < 4; r++)
            h[(size_t)(ib + r) * HID + n] = acc[nt][r];
        ushort4 o;
        o.x = bf16u(acc[nt][0]); o.y = bf16u(acc[nt][1]);
        o.z = bf16u(acc[nt][2]); o.w = bf16u(acc[nt][3]);
        *reinterpret_cast<ushort4*>(hT + (size_t)n * NN + ib) = o;
    }
}

// ---------------- s1[i] = h[i,:]@a1, s2[i] = h[i,:]@a2 ----------------
__global__ __launch_bounds__(256) void k_svec(const float* __restrict__ h,
                                              const float* __restrict__ a_edge,
                                              float* __restrict__ s1,
                                              float* __restrict__ s2) {
    int w = threadIdx.x >> 6, l = threadIdx.x & 63;
    int i = blockIdx.x * 4 + w;
    float4 hv = reinterpret_cast<const float4*>(h + (size_t)i * HID)[l];
    float4 a1 = reinterpret_cast<const float4*>(a_edge)[l];
    float4 a2 = reinterpret_cast<const float4*>(a_edge + HID)[l];
    float v1 = hv.x * a1.x + hv.y * a1.y + hv.z * a1.z + hv.w * a1.w;
    float v2 = hv.x * a2.x + hv.y * a2.y + hv.z * a2.z + hv.w * a2.w;
#pragma unroll
    for (int m = 32; m; m >>= 1) {
        v1 += __shfl_xor(v1, m);
        v2 += __shfl_xor(v2, m);
    }
    if (l == 0) { s1[i] = v1; s2[i] = v2; }
}

// ---------------- fused attention: U[i,:] += sum_j exp(w_ij) * h[j,:], denom[i] += sum_j exp(w_ij)
// grid (192 row-tiles, 4 j-chunks); block 256 = 4 waves; M=32, K-step=32, each wave N=64.
__global__ __launch_bounds__(256) void k_attn(const int* __restrict__ adj,
                                              const float* __restrict__ s1,
                                              const float* __restrict__ s2,
                                              const unsigned short* __restrict__ hT,
                                              float* __restrict__ U,
                                              float* __restrict__ denom) {
    __shared__ unsigned short Pf[2][1024];   // two 16x32 bf16 A-tiles in fragment order
    __shared__ float red[256];

    int t = threadIdx.x;
    int m = t & 31, kq = t >> 5;             // builder mapping: row m, k = 4*kq..4*kq+3
    int i0 = blockIdx.x * 32;
    int jbase = blockIdx.y * 1536;

    float s1v = s1[i0 + m];
    const int* arow = adj + (size_t)(i0 + m) * NN + jbase + kq * 4;
    const float* s2p = s2 + jbase + kq * 4;
    // LDS write slot (ushort index): frag (m>>4), lane (m&15)+16*(kq>>1), elem 4*(kq&1)
    int woff = (m >> 4) * 512 + ((m & 15) + 16 * (kq >> 1)) * 8 + (kq & 1) * 4;

    int w = t >> 6, l = t & 63, lm = l & 15, lq = l >> 4;
    const unsigned short* brow[4];
#pragma unroll
    for (int nt = 0; nt < 4; nt++)
        brow[nt] = hT + (size_t)(w * 64 + nt * 16 + lm) * NN + jbase + lq * 8;

    f32x4 acc[2][4] = {};
    float dsum = 0.f;

    for (int ks = 0; ks < 48; ks++) {
        int buf = ks & 1;
        int4 av = *reinterpret_cast<const int4*>(arow + ks * 32);
        float4 s2v = *reinterpret_cast<const float4*>(s2p + ks * 32);

        float sc, wv;
        sc = s1v + s2v.x; wv = sc > 0.f ? sc : 0.2f * sc;
        float p0 = av.x ? __expf(wv) : 0.f;
        sc = s1v + s2v.y; wv = sc > 0.f ? sc : 0.2f * sc;
        float p1 = av.y ? __expf(wv) : 0.f;
        sc = s1v + s2v.z; wv = sc > 0.f ? sc : 0.2f * sc;
        float p2 = av.z ? __expf(wv) : 0.f;
        sc = s1v + s2v.w; wv = sc > 0.f ? sc : 0.2f * sc;
        float p3 = av.w ? __expf(wv) : 0.f;
        dsum += p0 + p1 + p2 + p3;

        ushort4 pv;
        pv.x = bf16u(p0); pv.y = bf16u(p1); pv.z = bf16u(p2); pv.w = bf16u(p3);
        *reinterpret_cast<ushort4*>(&Pf[buf][woff]) = pv;

        __syncthreads();

        frag alo = *reinterpret_cast<const frag*>(&Pf[buf][l * 8]);
        frag ahi = *reinterpret_cast<const frag*>(&Pf[buf][512 + l * 8]);
        int kk = ks * 32;
#pragma unroll
        for (int nt = 0; nt < 4; nt++) {
            frag b = *reinterpret_cast<const frag*>(brow[nt] + kk);
            acc[0][nt] = __builtin_amdgcn_mfma_f32_16x16x32_bf16(alo, b, acc[0][nt], 0, 0, 0);
            acc[1][nt] = __builtin_amdgcn_mfma_f32_16x16x32_bf16(ahi, b, acc[1][nt], 0, 0, 0);
        }
        // no second sync: double-buffered (write buf^1 next iter; re-write of buf is
        // separated from this iter's reads by the next iter's __syncthreads)
    }

    // denominator reduction: 8 threads (kq) per row m
    red[t] = dsum;
    __syncthreads();
    if (t < 32) {
        float s = 0.f;
#pragma unroll
        for (int q = 0; q < 8; q++) s += red[t + 32 * q];
        atomicAdd(&denom[i0 + t], s);
    }
    // accumulate partial output
#pragma unroll
    for (int ff = 0; ff < 2; ff++) {
        int ib = i0 + ff * 16 + lq * 4;
#pragma unroll
        for (int nt = 0; nt < 4; nt++) {
            int n = w * 64 + nt * 16 + lm;
#pragma unroll
            for (int r = 0; r < 4; r++)
                atomicAdd(&U[(size_t)(ib + r) * HID + n], acc[ff][nt][r]);
        }
    }
}

// ---------------- normalize: out = U / denom ----------------
__global__ __launch_bounds__(256) void k_norm(const float* __restrict__ U,
                                              const float* __restrict__ denom,
                                              float* __restrict__ out) {
    int i = blockIdx.x, t = threadIdx.x;
    float dn = denom[i];
    float u = U[(size_t)i * HID + t];
    out[(size_t)i * HID + t] = (dn != 0.f) ? u / dn : 0.f;
}

extern "C" void kernel_launch(void* const* d_in, const int* in_sizes, int n_in,
                              void* d_out, int out_size, void* d_ws, size_t ws_size,
                              hipStream_t stream) {
    const float* X      = (const float*)d_in[0];   // 6144x1024
    const float* W      = (const float*)d_in[1];   // 1024x256
    const float* a_edge = (const float*)d_in[2];   // 512
    const int*   adj    = (const int*)d_in[3];     // 6144x6144
    float* out = (float*)d_out;

    float* U     = (float*)d_ws;                        // N*HID f32
    float* denom = U + (size_t)NN * HID;                // N f32
    float* h     = denom + NN;                          // N*HID f32
    unsigned short* hT = (unsigned short*)(h + (size_t)NN * HID);  // HID*N bf16
    unsigned short* Xb = hT + (size_t)HID * NN;         // N*INPUT bf16
    unsigned short* Wt = Xb + (size_t)NN * INPUT;       // HID*INPUT bf16
    float* s1 = (float*)(Wt + (size_t)HID * INPUT);     // N
    float* s2 = s1 + NN;                                // N

    hipMemsetAsync(U, 0, ((size_t)NN * HID + NN) * sizeof(float), stream);
    k_convert_x<<<NN * INPUT / 1024, 256, 0, stream>>>(X, Xb);
    k_convert_w<<<INPUT * HID / 256, 256, 0, stream>>>(W, Wt);
    k_gemm1<<<dim3(NN / 64, HID / 64), 256, 0, stream>>>(Xb, Wt, h, hT);
    k_svec<<<NN / 4, 256, 0, stream>>>(h, a_edge, s1, s2);
    k_attn<<<dim3(NN / 32, 4), 256, 0, stream>>>(adj, s1, s2, hT, U, denom);
    k_norm<<<NN, 256, 0, stream>>>(U, denom, out);
}